// Round 5
// baseline (24416.432 us; speedup 1.0000x reference)
//
#include <hip/hip_runtime.h>

// R7: XCD-island chains — L2-scope tag-in-data recurrence.
//
// Evidence: R2(13.3ms)/R4(26ms)/R5(19ms)/R6(13.9ms) show the tick cost is the
// system-scope leg latency (~0.6-0.9us each, m126), not protocol structure.
// L2 hits are ~85ns (m125). So: put each chain's all-gather inside ONE XCD.
//  - membership: ticketed on s_getreg(XCC_ID) (R4-proven mechanism) -> all 8
//    blocks of a chain are on the chain's XCD by construction.
//  - protocol: R6's tag-in-data packets (8B [h,h,tag], fire-and-forget, bulk
//    load + tag verify). NO ordering assumptions, only eventual visibility.
//  - scope: intra-chain packets sc0 (bypass L1, served by the XCD L2; a miss
//    falls through to IF$ -> correct either way). Cross-chain (L0->L1) stays
//    system-scope, ring-4 + aggregated backpressure -> off critical path.
//  - gating: two-generation epoch-keyed sc0 probe per chain; any anomaly ->
//    SYS fallback (R6-equivalent, proven-correct).
// Footprint: 32K ctrl + 256K hbL2 + 256K hbSys = 544 KB (= R6's proven size).

typedef _Float16 half8 __attribute__((ext_vector_type(8)));
typedef float f32x4 __attribute__((ext_vector_type(4)));
typedef unsigned u32x4 __attribute__((ext_vector_type(4)));
typedef unsigned long long ull;

#define B_ 32
#define S_ 2048
#define D_ 256
#define H_ 256
#define G_ 1024
#define OUT0 (B_*S_*2*H_)   /* 33554432 */

#define HL2_SLOTS 2   /* intra-chain ring (safety: publish gen t+1 requires   */
                      /* detect of gen t => everyone consumed gen t-1)        */
#define HSY_SLOTS 4   /* L0->L1 ring, guarded by agg backpressure             */

__device__ __forceinline__ size_t l2off(int chain,int s,int row,int pkt){
  return ((size_t)(((chain*HL2_SLOTS)+s)*B_ + row)*128 + pkt)*8;
}
__device__ __forceinline__ size_t syoff(int dir,int s,int row,int pkt){
  return ((size_t)(((dir*HSY_SLOTS)+s)*B_ + row)*128 + pkt)*8;
}

__device__ __forceinline__ float sigmoidf_(float v){ return 1.f/(1.f+__expf(-v)); }
__device__ __forceinline__ float tanhf_(float v){ return 2.f/(1.f+__expf(-2.f*v)) - 1.f; }

// ---- packet primitives ----------------------------------------------------
template<bool FAST>
__device__ __forceinline__ ull ld_probe(const void* p){
  ull v;
  if constexpr (FAST)
    asm volatile("global_load_dwordx2 %0, %1, off sc0\n\ts_waitcnt vmcnt(0)"
                 : "=v"(v) : "v"(p) : "memory");
  else
    asm volatile("global_load_dwordx2 %0, %1, off sc0 sc1\n\ts_waitcnt vmcnt(0)"
                 : "=v"(v) : "v"(p) : "memory");
  return v;
}

// 16 dwordx4 loads (= 32 packets = one wave's 8 K-frags with tags) from one
// per-lane base, constant offsets. NO wait inside: caller must issue
// s_waitcnt vmcnt(0) + sched_barrier(0) before consuming g[].
#define LD16(SCOPE) \
  asm volatile( \
    "global_load_dwordx4 %0, %16, off " SCOPE "\n\t" \
    "global_load_dwordx4 %1, %16, off offset:16 " SCOPE "\n\t" \
    "global_load_dwordx4 %2, %16, off offset:128 " SCOPE "\n\t" \
    "global_load_dwordx4 %3, %16, off offset:144 " SCOPE "\n\t" \
    "global_load_dwordx4 %4, %16, off offset:256 " SCOPE "\n\t" \
    "global_load_dwordx4 %5, %16, off offset:272 " SCOPE "\n\t" \
    "global_load_dwordx4 %6, %16, off offset:384 " SCOPE "\n\t" \
    "global_load_dwordx4 %7, %16, off offset:400 " SCOPE "\n\t" \
    "global_load_dwordx4 %8, %16, off offset:512 " SCOPE "\n\t" \
    "global_load_dwordx4 %9, %16, off offset:528 " SCOPE "\n\t" \
    "global_load_dwordx4 %10, %16, off offset:640 " SCOPE "\n\t" \
    "global_load_dwordx4 %11, %16, off offset:656 " SCOPE "\n\t" \
    "global_load_dwordx4 %12, %16, off offset:768 " SCOPE "\n\t" \
    "global_load_dwordx4 %13, %16, off offset:784 " SCOPE "\n\t" \
    "global_load_dwordx4 %14, %16, off offset:896 " SCOPE "\n\t" \
    "global_load_dwordx4 %15, %16, off offset:912 " SCOPE \
    : "=&v"(g[0]),"=&v"(g[1]),"=&v"(g[2]),"=&v"(g[3]), \
      "=&v"(g[4]),"=&v"(g[5]),"=&v"(g[6]),"=&v"(g[7]), \
      "=&v"(g[8]),"=&v"(g[9]),"=&v"(g[10]),"=&v"(g[11]), \
      "=&v"(g[12]),"=&v"(g[13]),"=&v"(g[14]),"=&v"(g[15]) \
    : "v"(p) : "memory")

template<bool FAST>
__device__ __forceinline__ void ld_bulk16(const void* p, u32x4 g[16]){
  if constexpr (FAST) { LD16("sc0"); } else { LD16("sc0 sc1"); }
}

template<bool FAST>
__device__ __forceinline__ void st_pub4(void* p, ull p0, ull p1, ull p2, ull p3){
  if constexpr (FAST)
    asm volatile(
      "global_store_dwordx2 %0, %1, off sc0\n\t"
      "global_store_dwordx2 %0, %2, off offset:1024 sc0\n\t"
      "global_store_dwordx2 %0, %3, off offset:2048 sc0\n\t"
      "global_store_dwordx2 %0, %4, off offset:3072 sc0"
      :: "v"(p),"v"(p0),"v"(p1),"v"(p2),"v"(p3) : "memory");
  else
    asm volatile(
      "global_store_dwordx2 %0, %1, off sc0 sc1\n\t"
      "global_store_dwordx2 %0, %2, off offset:1024 sc0 sc1\n\t"
      "global_store_dwordx2 %0, %3, off offset:2048 sc0 sc1\n\t"
      "global_store_dwordx2 %0, %4, off offset:3072 sc0 sc1"
      :: "v"(p),"v"(p0),"v"(p1),"v"(p2),"v"(p3) : "memory");
}

__device__ __forceinline__ void st_tok(void* p, unsigned v){
  asm volatile("global_store_dword %0, %1, off sc0" :: "v"(p), "v"(v) : "memory");
}
__device__ __forceinline__ int ld_tok(const void* p){
  int v;
  asm volatile("global_load_dword %0, %1, off sc0\n\ts_waitcnt vmcnt(0)"
               : "=v"(v) : "v"(p) : "memory");
  return v;
}

__device__ __forceinline__ bool verify16(const u32x4 g[16], unsigned tag){
  bool ok = true;
#pragma unroll
  for (int i = 0; i < 16; ++i) ok &= (g[i][1] == tag) & (g[i][3] == tag);
  return ok;
}

// ws layout (544 KB total, = R6's proven footprint):
//  0: cnt[4] (stride 16)   1024: agg[4] (stride 16)   2048: verd[32] (stride 16)
//  4096: toks[32] (stride 16)   8192: epoch   32768: hbL2 (256K)   +256K: hbSys
__global__ __launch_bounds__(64) void lstm_prep(int* __restrict__ cnt,
                                                int* __restrict__ agg,
                                                int* __restrict__ verd,
                                                unsigned* __restrict__ epoch)
{
  int i = threadIdx.x;
  if (i == 0)
    __hip_atomic_fetch_add(epoch, 1u, __ATOMIC_RELAXED, __HIP_MEMORY_SCOPE_SYSTEM);
  if (i < 4) {
    __hip_atomic_store(&cnt[i*16], 0, __ATOMIC_RELAXED, __HIP_MEMORY_SCOPE_SYSTEM);
    __hip_atomic_store(&agg[i*16], 0, __ATOMIC_RELAXED, __HIP_MEMORY_SCOPE_SYSTEM);
  }
  if (i < 32)
    __hip_atomic_store(&verd[i*16], -1, __ATOMIC_RELAXED, __HIP_MEMORY_SCOPE_SYSTEM);
}

template<bool FAST>
__device__ __forceinline__ void run_chain(
    const float* __restrict__ x, const float* __restrict__ enc_h,
    const float* __restrict__ enc_c,
    const float* __restrict__ Wih, const float* __restrict__ Whh,
    const float* __restrict__ bih, const float* __restrict__ bhh,
    float* __restrict__ out, int* __restrict__ agg,
    char* __restrict__ hbL2, char* __restrict__ hbSys,
    unsigned EB, int chain, int mb, int tid)
{
  const int dir   = chain >> 1;
  const int layer = chain & 1;
  const int m     = mb & 1;
  const int wv    = tid >> 6;
  const int cg    = (mb >> 1)*4 + wv;     // colgroup 0..15
  const int c0    = cg << 4;
  const int lane  = tid & 63;
  const int quad  = lane >> 4;
  const int lq    = lane & 15;

  // ---- resident B-fragments (R2-proven layout) ----
  half8 bf[4][16];
#pragma unroll
  for (int q = 0; q < 4; ++q) {
    const int n_g = q*256 + c0 + lq;
    const float* wihr = Wih + (size_t)layer*G_*256 + (size_t)n_g*256 + quad*8;
    const float* whhr = Whh + (size_t)layer*G_*256 + (size_t)n_g*256 + quad*8;
#pragma unroll
    for (int kk = 0; kk < 16; ++kk) {
      const float* src = (kk < 8) ? (wihr + kk*32) : (whhr + (kk-8)*32);
      f32x4 w0 = *(const f32x4*)src;
      f32x4 w1 = *(const f32x4*)(src+4);
      half8 hv;
      hv[0]=(_Float16)w0[0]; hv[1]=(_Float16)w0[1]; hv[2]=(_Float16)w0[2]; hv[3]=(_Float16)w0[3];
      hv[4]=(_Float16)w1[0]; hv[5]=(_Float16)w1[1]; hv[6]=(_Float16)w1[2]; hv[7]=(_Float16)w1[3];
      bf[q][kk] = hv;
    }
  }

  float bias[4];
#pragma unroll
  for (int q = 0; q < 4; ++q) {
    const int n_g = q*256 + c0 + lq;
    bias[q] = bih[layer*G_ + n_g] + bhh[layer*G_ + n_g];
  }

  f32x4 cst;
#pragma unroll
  for (int r = 0; r < 4; ++r) {
    const int b = m*16 + quad*4 + r;
    cst[r] = enc_c[b*(2*H_) + dir*H_ + c0 + lq];
  }

  const int arow = m*16 + lq;
  const float* xrowBase = x + (size_t)arow*S_*D_;
  int* aggP = agg + (dir*2 + m)*16;

  // ---- gen-0 self-publish (slot 0, tag EB) from enc_h ----
  {
    const int pkt = cg*8 + (lq >> 1);
    if (!(lq & 1)) {
      ull pk[4];
#pragma unroll
      for (int r = 0; r < 4; ++r) {
        const int b = m*16 + quad*4 + r;
        const int col = c0 + lq;
        _Float16 lo = (_Float16)enc_h[b*(2*H_) + dir*H_ + col];
        _Float16 hi = (_Float16)enc_h[b*(2*H_) + dir*H_ + col + 1];
        unsigned pair = (unsigned)__builtin_bit_cast(unsigned short, lo)
                      | ((unsigned)__builtin_bit_cast(unsigned short, hi) << 16);
        pk[r] = ((ull)EB << 32) | pair;
      }
      st_pub4<FAST>(hbL2 + l2off(chain, 0, m*16 + quad*4, pkt), pk[0],pk[1],pk[2],pk[3]);
    }
  }

  u32x4 gA[16], gB[16];
  // L1: prefetch upstream gen 1 (slot 1) — drained by the first spin.
  if (layer == 1)
    ld_bulk16<false>(hbSys + syoff(dir, 1, arow, quad*4), gB);

  bool dead = false;

  for (int t = 0; t < S_; ++t) {
    const unsigned tagT = EB + (unsigned)t;
    half8 ain[8], arec[8];

    if (layer == 0) {
      // x loads before the spin (independent of recurrence)
      const float* xr = xrowBase + (size_t)t*D_;
#pragma unroll
      for (int kk = 0; kk < 8; ++kk) {
        const int k = kk*32 + quad*8;
        half8 hv;
        if (dir == 0) {
          f32x4 a0 = *(const f32x4*)(xr + k);
          f32x4 a1 = *(const f32x4*)(xr + k + 4);
          hv[0]=(_Float16)a0[0]; hv[1]=(_Float16)a0[1]; hv[2]=(_Float16)a0[2]; hv[3]=(_Float16)a0[3];
          hv[4]=(_Float16)a1[0]; hv[5]=(_Float16)a1[1]; hv[6]=(_Float16)a1[2]; hv[7]=(_Float16)a1[3];
        } else {
          const float* p = xr + (248 - k);
          f32x4 a0 = *(const f32x4*)p;
          f32x4 a1 = *(const f32x4*)(p + 4);
          hv[0]=(_Float16)a1[3]; hv[1]=(_Float16)a1[2]; hv[2]=(_Float16)a1[1]; hv[3]=(_Float16)a1[0];
          hv[4]=(_Float16)a0[3]; hv[5]=(_Float16)a0[2]; hv[6]=(_Float16)a0[1]; hv[7]=(_Float16)a0[0];
        }
        ain[kk] = hv;
      }
    }

    // ---- local detect: one probe packet per same-m member (L2-scope) ----
    {
      const void* pp = hbL2 + l2off(chain, t & 1, m*16 + 15, (lane & 15)*8 + 7);
      int guard = 0;
      for (;;) {
        ull v = ld_probe<FAST>(pp);
        if (__all((unsigned)(v >> 32) == tagT)) break;
        if (++guard > (1 << 20)) { dead = true; break; }
      }
    }
    if (dead) break;
    __builtin_amdgcn_sched_barrier(0);

    if (layer == 1) {
      // aggregate progress for L0's backpressure (one writer per (dir,m))
      if (cg == 0 && lane == 0)
        __hip_atomic_store(aggP, t, __ATOMIC_RELAXED, __HIP_MEMORY_SCOPE_SYSTEM);
    } else {
      // backpressure vs hbSys ring-4: every 2nd tick require agg >= t-2
      if (!(t & 1)) {
        int guard = 0;
        while (__hip_atomic_load(aggP, __ATOMIC_RELAXED, __HIP_MEMORY_SCOPE_SYSTEM) < t - 2) {
          if (++guard > (1 << 20)) { dead = true; break; }
        }
        if (dead) break;
      }
    }

    // ---- bulk load + tag verify (retry on partial arrival) ----
    bool okB = (layer == 0) || verify16(gB, tagT + 1);  // prefetched upstream
    {
      const void* lb = hbL2 + l2off(chain, t & 1, arow, quad*4);
      const void* ub = hbSys + syoff(dir, (t + 1) & 3, arow, quad*4);
      int guard = 0;
      for (;;) {
        ld_bulk16<FAST>(lb, gA);
        if (!okB) ld_bulk16<false>(ub, gB);
        asm volatile("s_waitcnt vmcnt(0)" ::: "memory");
        __builtin_amdgcn_sched_barrier(0);
        bool ok = verify16(gA, tagT);
        if (!okB) okB = verify16(gB, tagT + 1);
        if (__all(ok & okB)) break;
        if (++guard > (1 << 20)) { dead = true; break; }
      }
      if (dead) break;
    }
#pragma unroll
    for (int kk = 0; kk < 8; ++kk) {
      u32x4 d = { gA[2*kk][0], gA[2*kk][2], gA[2*kk+1][0], gA[2*kk+1][2] };
      arec[kk] = __builtin_bit_cast(half8, d);
    }
    if (layer == 1) {
#pragma unroll
      for (int kk = 0; kk < 8; ++kk) {
        u32x4 d = { gB[2*kk][0], gB[2*kk][2], gB[2*kk+1][0], gB[2*kk+1][2] };
        ain[kk] = __builtin_bit_cast(half8, d);
      }
    }

    f32x4 acc0 = {bias[0],bias[0],bias[0],bias[0]};
    f32x4 acc1 = {bias[1],bias[1],bias[1],bias[1]};
    f32x4 acc2 = {bias[2],bias[2],bias[2],bias[2]};
    f32x4 acc3 = {bias[3],bias[3],bias[3],bias[3]};
#pragma unroll
    for (int kk = 0; kk < 8; ++kk) {
      acc0 = __builtin_amdgcn_mfma_f32_16x16x32_f16(ain[kk], bf[0][kk], acc0, 0,0,0);
      acc1 = __builtin_amdgcn_mfma_f32_16x16x32_f16(ain[kk], bf[1][kk], acc1, 0,0,0);
      acc2 = __builtin_amdgcn_mfma_f32_16x16x32_f16(ain[kk], bf[2][kk], acc2, 0,0,0);
      acc3 = __builtin_amdgcn_mfma_f32_16x16x32_f16(ain[kk], bf[3][kk], acc3, 0,0,0);
    }
#pragma unroll
    for (int kk = 0; kk < 8; ++kk) {
      acc0 = __builtin_amdgcn_mfma_f32_16x16x32_f16(arec[kk], bf[0][kk+8], acc0, 0,0,0);
      acc1 = __builtin_amdgcn_mfma_f32_16x16x32_f16(arec[kk], bf[1][kk+8], acc1, 0,0,0);
      acc2 = __builtin_amdgcn_mfma_f32_16x16x32_f16(arec[kk], bf[2][kk+8], acc2, 0,0,0);
      acc3 = __builtin_amdgcn_mfma_f32_16x16x32_f16(arec[kk], bf[3][kk+8], acc3, 0,0,0);
    }

    float hval[4];
#pragma unroll
    for (int r = 0; r < 4; ++r) {
      float si = sigmoidf_(acc0[r]);
      float sf = sigmoidf_(acc1[r]);
      float tg = tanhf_  (acc2[r]);
      float so = sigmoidf_(acc3[r]);
      float cn = sf*cst[r] + si*tg;
      cst[r] = cn;
      hval[r] = so*tanhf_(cn);
    }

    // ---- publish gen t+1 (fire-and-forget tagged packets) ----
    {
      const unsigned tagN = tagT + 1;
      ull pk[4];
#pragma unroll
      for (int r = 0; r < 4; ++r) {
        float partner = __shfl_xor(hval[r], 1);
        unsigned short lo = __builtin_bit_cast(unsigned short, (_Float16)hval[r]);
        unsigned short hi = __builtin_bit_cast(unsigned short, (_Float16)partner);
        pk[r] = ((ull)tagN << 32) | ((unsigned)lo | ((unsigned)hi << 16));
      }
      if (!(lq & 1)) {
        const int pkt = cg*8 + (lq >> 1);
        st_pub4<FAST>(hbL2 + l2off(chain, (t+1) & 1, m*16 + quad*4, pkt),
                      pk[0],pk[1],pk[2],pk[3]);
        if (layer == 0)
          st_pub4<false>(hbSys + syoff(dir, (t+1) & 3, m*16 + quad*4, pkt),
                         pk[0],pk[1],pk[2],pk[3]);
      }
    }

    if (layer == 1) {
      // prefetch next upstream (gen t+2, slot (t+2)&3) — hidden under next spin
      if (t < S_-1)
        ld_bulk16<false>(hbSys + syoff(dir, (t + 2) & 3, arow, quad*4), gB);
      // out[] — off the critical path
      const int colg = dir*256 + c0 + lq;
#pragma unroll
      for (int r = 0; r < 4; ++r) {
        const int b = m*16 + quad*4 + r;
        out[((size_t)b*S_ + t)*(2*H_) + colg] = hval[r];
      }
      if (t == S_-1) {
#pragma unroll
        for (int r = 0; r < 4; ++r) {
          const int b = m*16 + quad*4 + r;
          out[OUT0 + (size_t)b*(2*H_) + colg] = hval[r];
          out[OUT0 + B_*2*H_ + (size_t)b*(2*H_) + colg] = cst[r];
        }
      }
    }
  }
}

__global__ __launch_bounds__(256,1) void lstm_main(
    const float* __restrict__ x,
    const float* __restrict__ enc_h,
    const float* __restrict__ enc_c,
    const float* __restrict__ Wih_f, const float* __restrict__ Whh_f,
    const float* __restrict__ bih_f, const float* __restrict__ bhh_f,
    const float* __restrict__ Wih_b, const float* __restrict__ Whh_b,
    const float* __restrict__ bih_b, const float* __restrict__ bhh_b,
    float* __restrict__ out,
    int* __restrict__ cnt, int* __restrict__ agg,
    int* __restrict__ verd, int* __restrict__ toks,
    unsigned* __restrict__ epoch,
    char* __restrict__ hbL2, char* __restrict__ hbSys)
{
  __shared__ int sXcc, sTk, sFast;
  const int tid = threadIdx.x;

  if (tid == 0) {
    unsigned xcc;
    asm volatile("s_getreg_b32 %0, hwreg(HW_REG_XCC_ID)" : "=s"(xcc));
    xcc &= 7;
    int tk = 999;
    if (xcc < 4)
      tk = __hip_atomic_fetch_add(&cnt[xcc*16], 1, __ATOMIC_RELAXED,
                                  __HIP_MEMORY_SCOPE_SYSTEM);
    sXcc = (int)xcc; sTk = tk;
  }
  __syncthreads();
  const int chain = sXcc;
  const int mb    = sTk;
  if (chain >= 4 || mb >= 8) return;

  const unsigned E = __hip_atomic_load(epoch, __ATOMIC_RELAXED,
                                       __HIP_MEMORY_SCOPE_SYSTEM);

  // ---- sc0/L2 visibility probe (wave 0), two generations, epoch-keyed ----
  if (tid < 64) {
    bool ok = true;
#pragma unroll 1
    for (int phase = 1; phase <= 2; ++phase) {
      const unsigned tgt = E*2u + (unsigned)phase;
      if (tid == 0) st_tok(&toks[(chain*8 + mb)*16], tgt);
      int guard = 0;
      for (;;) {
        int v = ld_tok(&toks[(chain*8 + (tid & 7))*16]);
        if (__all((int)((unsigned)v - tgt) >= 0)) break;
        if (++guard > (1 << 15)) { ok = false; break; }
      }
      if (!ok) break;
    }
    if (tid == 0)
      __hip_atomic_store(&verd[(chain*8 + mb)*16], ok ? 1 : 0,
                         __ATOMIC_RELAXED, __HIP_MEMORY_SCOPE_SYSTEM);
    int vd = -1; bool have = true;
    {
      int guard = 0;
      for (;;) {
        vd = __hip_atomic_load(&verd[(chain*8 + (tid & 7))*16],
                               __ATOMIC_RELAXED, __HIP_MEMORY_SCOPE_SYSTEM);
        if (__all(vd >= 0)) break;
        if (++guard > (1 << 20)) { have = false; break; }
      }
    }
    if (tid == 0) sFast = (have && __all(vd == 1)) ? 1 : 0;
  }
  __syncthreads();
  const bool fast = (sFast != 0);

  const int dir = chain >> 1;
  const float* Wih = dir ? Wih_b : Wih_f;
  const float* Whh = dir ? Whh_b : Whh_f;
  const float* bih = dir ? bih_b : bih_f;
  const float* bhh = dir ? bhh_b : bhh_f;
  const unsigned EB = E * 4096u;

  if (fast)
    run_chain<true >(x, enc_h, enc_c, Wih, Whh, bih, bhh, out, agg,
                     hbL2, hbSys, EB, chain, mb, tid);
  else
    run_chain<false>(x, enc_h, enc_c, Wih, Whh, bih, bhh, out, agg,
                     hbL2, hbSys, EB, chain, mb, tid);
}

extern "C" void kernel_launch(void* const* d_in, const int* in_sizes, int n_in,
                              void* d_out, int out_size, void* d_ws, size_t ws_size,
                              hipStream_t stream) {
  const float* x     = (const float*)d_in[0];
  const float* enc_h = (const float*)d_in[1];
  const float* enc_c = (const float*)d_in[2];
  const float* Wih_f = (const float*)d_in[3];
  const float* Whh_f = (const float*)d_in[4];
  const float* bih_f = (const float*)d_in[5];
  const float* bhh_f = (const float*)d_in[6];
  const float* Wih_b = (const float*)d_in[7];
  const float* Whh_b = (const float*)d_in[8];
  const float* bih_b = (const float*)d_in[9];
  const float* bhh_b = (const float*)d_in[10];

  int*      cnt   = (int*)d_ws;
  int*      agg   = (int*)((char*)d_ws + 1024);
  int*      verd  = (int*)((char*)d_ws + 2048);
  int*      toks  = (int*)((char*)d_ws + 4096);
  unsigned* epoch = (unsigned*)((char*)d_ws + 8192);
  char*     hbL2  = (char*)d_ws + 32768;              // 256 KB
  char*     hbSys = (char*)d_ws + 32768 + 262144;     // 256 KB

  lstm_prep<<<1, 64, 0, stream>>>(cnt, agg, verd, epoch);
  lstm_main<<<512, 256, 0, stream>>>(x, enc_h, enc_c,
                                     Wih_f, Whh_f, bih_f, bhh_f,
                                     Wih_b, Whh_b, bih_b, bhh_b,
                                     (float*)d_out,
                                     cnt, agg, verd, toks, epoch, hbL2, hbSys);
}